// Round 20
// baseline (124.393 us; speedup 1.0000x reference)
//
#include <hip/hip_runtime.h>
#include <stdint.h>

#define EPSF 1e-5f

typedef float f32x4 __attribute__((ext_vector_type(4)));
typedef short bf16x8 __attribute__((ext_vector_type(8)));   // 8 bf16 in 4 VGPRs

__device__ __forceinline__ float softplus_f(float x) {
    return x > 20.f ? x : log1pf(expf(x));
}

// fp32 -> bf16 RNE (finite inputs)
__device__ __forceinline__ unsigned short f2bf(float f) {
    union { float f; unsigned int u; } v; v.f = f;
    unsigned int r = v.u + 0x7FFFu + ((v.u >> 16) & 1u);
    return (unsigned short)(r >> 16);
}
__device__ __forceinline__ float bf2f(unsigned short u) {
    union { unsigned int i; float f; } v; v.i = ((unsigned int)u) << 16;
    return v.f;
}
__device__ __forceinline__ int cvt_pk_bf16(float a, float b) {
    int d;
    asm("v_cvt_pk_bf16_f32 %0, %1, %2" : "=v"(d) : "v"(a), "v"(b));
    return d;
}
__device__ __forceinline__ int bperm(int byte_addr, int v) {
    return __builtin_amdgcn_ds_bpermute(byte_addr, v);
}
__device__ __forceinline__ float bpermf(int byte_addr, float v) {
    return __int_as_float(__builtin_amdgcn_ds_bpermute(byte_addr, __float_as_int(v)));
}
// single-instruction HW transcendentals (~1 ulp)
__device__ __forceinline__ float rcp_f(float x)  { float d; asm("v_rcp_f32 %0, %1"  : "=v"(d) : "v"(x)); return d; }
__device__ __forceinline__ float sqrt_f(float x) { float d; asm("v_sqrt_f32 %0, %1" : "=v"(d) : "v"(x)); return d; }
__device__ __forceinline__ float log2_f(float x) { float d; asm("v_log_f32 %0, %1"  : "=v"(d) : "v"(x)); return d; }
__device__ __forceinline__ float exp2_f(float x) { float d; asm("v_exp_f32 %0, %1"  : "=v"(d) : "v"(x)); return d; }

// ---------------- fused fp32 -> bf16 convert, float4-vectorized (r13) ----------------
__global__ __launch_bounds__(256) void k_f2b_all(const float* __restrict__ x,
                                                 const float* __restrict__ W0, const float* __restrict__ W1,
                                                 const float* __restrict__ W2, const float* __restrict__ W3,
                                                 unsigned short* __restrict__ xb,
                                                 unsigned short* __restrict__ o0, unsigned short* __restrict__ o1,
                                                 unsigned short* __restrict__ o2, unsigned short* __restrict__ o3) {
    const int NX4 = 524288;
    const int NW4 = 262144;
    int i = blockIdx.x * 256 + threadIdx.x;
    int stride = gridDim.x * 256;
    for (; i < NX4 + 4 * NW4; i += stride) {
        const float4* src;
        ushort4* dst;
        if (i < NX4) {
            src = (const float4*)x + i;
            dst = (ushort4*)xb + i;
        } else {
            int j = i - NX4;
            int sel = j >> 18, off = j & (NW4 - 1);
            const float* s = sel == 0 ? W0 : sel == 1 ? W1 : sel == 2 ? W2 : W3;
            unsigned short* d = sel == 0 ? o0 : sel == 1 ? o1 : sel == 2 ? o2 : o3;
            src = (const float4*)s + off;
            dst = (ushort4*)d + off;
        }
        float4 v = *src;
        ushort4 o;
        o.x = f2bf(v.x); o.y = f2bf(v.y); o.z = f2bf(v.z); o.w = f2bf(v.w);
        *dst = o;
    }
}

#if defined(__has_builtin)
#if __has_builtin(__builtin_amdgcn_global_load_lds)
#define HAVE_GLL 1
#endif
#endif

// ---------------- bf16 MFMA GEMM, 64x64 tile + FUSED exp_map epilogue ----------------
// B = [3072][K] concat; grid 32x48 = 1536 blocks = 6 blocks/CU (2x the 128x64
// config's latency hiding — r17's verified out-GEMM mechanism applied to QKV).
// Each tile = ONE head (64 cols) x 64 tokens:
//   sel==0/1 (Q/K): per-token norm in-epilogue (shfl over fr + 1KB LDS cross-wave
//   combine), exp_map applied, MAPPED bf16 + ns/ds written.
//   sel==2 (V): transposed store into Vtg (r18-verified pattern).
__global__ __launch_bounds__(256) void k_gemm_qkv(const unsigned short* __restrict__ A,
                                                  const unsigned short* __restrict__ B,
                                                  unsigned short* __restrict__ Qo,
                                                  unsigned short* __restrict__ Ko,
                                                  unsigned short* __restrict__ Vtg,
                                                  float* __restrict__ xns, float* __restrict__ xds,
                                                  float* __restrict__ yns, float* __restrict__ yds,
                                                  const float* __restrict__ pLogC,
                                                  int M, int N, int K) {
    __shared__ __align__(16) unsigned short As[64 * 32];
    __shared__ __align__(16) unsigned short Bs[64 * 32];
    const int tid  = threadIdx.x;
    const int lane = tid & 63;
    const int w    = tid >> 6;
    const int wr   = w >> 1, wc = w & 1;
    const int fr   = lane & 15;
    const int fg   = lane >> 4;
    const int nbx  = N >> 6;
    const int bx   = blockIdx.x % nbx;
    const int by   = blockIdx.x / nbx;
    const int bm0  = by * 64, bn0 = bx * 64;

    const int lrow = lane >> 2;
    const int lcol = (lane & 3) * 8;

    f32x4 acc[2][2] = {};

    for (int kk = 0; kk < K; kk += 32) {
#ifdef HAVE_GLL
        {
            const unsigned short* gp0 = &A[(size_t)(bm0 + w * 16 + lrow) * K + kk + lcol];
            __builtin_amdgcn_global_load_lds((const __attribute__((address_space(1))) void*)gp0,
                (__attribute__((address_space(3))) void*)&As[(w * 16) * 32], 16, 0, 0);
            const unsigned short* gp1 = &B[(size_t)(bn0 + w * 16 + lrow) * K + kk + lcol];
            __builtin_amdgcn_global_load_lds((const __attribute__((address_space(1))) void*)gp1,
                (__attribute__((address_space(3))) void*)&Bs[(w * 16) * 32], 16, 0, 0);
        }
#else
        {
            uint4 a0 = *(const uint4*)&A[(size_t)(bm0 + w * 16 + lrow) * K + kk + lcol];
            uint4 b0 = *(const uint4*)&B[(size_t)(bn0 + w * 16 + lrow) * K + kk + lcol];
            *(uint4*)&As[(w * 16 + lrow) * 32 + lcol] = a0;
            *(uint4*)&Bs[(w * 16 + lrow) * 32 + lcol] = b0;
        }
#endif
        __syncthreads();

        bf16x8 av[2], bv[2];
#pragma unroll
        for (int m = 0; m < 2; m++)
            av[m] = *(const bf16x8*)&As[(wr * 32 + m * 16 + fr) * 32 + fg * 8];
#pragma unroll
        for (int n = 0; n < 2; n++)
            bv[n] = *(const bf16x8*)&Bs[(wc * 32 + n * 16 + fr) * 32 + fg * 8];
#pragma unroll
        for (int m = 0; m < 2; m++)
#pragma unroll
            for (int n = 0; n < 2; n++)
                acc[m][n] = __builtin_amdgcn_mfma_f32_16x16x32_bf16(av[m], bv[n], acc[m][n], 0, 0, 0);
        __syncthreads();
    }

    const int crow0 = bm0 + wr * 32 + fg * 4;
    const int sel = bn0 >> 10;
    if (sel == 2) {
        // V tile: transposed store (r18-verified)
        const int col0 = (bn0 & 1023) + wc * 32 + fr;
#pragma unroll
        for (int m = 0; m < 2; m++)
#pragma unroll
            for (int n = 0; n < 2; n++) {
                ushort4 o;
                o.x = f2bf(acc[m][n][0]); o.y = f2bf(acc[m][n][1]);
                o.z = f2bf(acc[m][n][2]); o.w = f2bf(acc[m][n][3]);
                *(ushort4*)&Vtg[(size_t)(col0 + n * 16) * 2048 + crow0 + m * 16] = o;
            }
    } else {
        // Q/K tile: fused exp_map (tile = one head x 64 tokens)
        const float c  = softplus_f(pLogC[0]);
        const float sc = sqrtf(c);
        float* ns = sel == 0 ? xns : yns;
        float* ds = sel == 0 ? xds : yds;
        unsigned short* Cp = sel == 0 ? Qo : Ko;
        const int hh  = (bn0 & 1023) >> 6;

        // per-(m,r) partial: sum of squares over this wave's 32 cols
        float ps[2][4];
#pragma unroll
        for (int m = 0; m < 2; m++)
#pragma unroll
            for (int r = 0; r < 4; r++) {
                float s = acc[m][0][r] * acc[m][0][r] + acc[m][1][r] * acc[m][1][r];
#pragma unroll
                for (int o = 1; o < 16; o <<= 1) s += __shfl_xor(s, o);
                ps[m][r] = s;
            }
        // cross-wave (wc) combine via reused As LDS: part[(wr*2+wc)*64 + localrow]
        float* part = (float*)As;
        if (fr == 0)
#pragma unroll
            for (int m = 0; m < 2; m++)
#pragma unroll
                for (int r = 0; r < 4; r++)
                    part[(wr * 2 + wc) * 64 + wr * 32 + m * 16 + fg * 4 + r] = ps[m][r];
        __syncthreads();

#pragma unroll
        for (int m = 0; m < 2; m++)
#pragma unroll
            for (int r = 0; r < 4; r++) {
                int lr_ = wr * 32 + m * 16 + fg * 4 + r;     // local token 0..63
                float n2 = part[(wr * 2) * 64 + lr_] + part[(wr * 2 + 1) * 64 + lr_];
                float nn = fmaxf(sqrtf(n2), EPSF);
                float u  = sc * nn;
                float e  = __expf(-2.f * u);
                float th = (1.f - e) / (1.f + e);    // tanh(u), stable
                float f  = th / (sc * nn);
                int token = crow0 + m * 16 + r;
#pragma unroll
                for (int n = 0; n < 2; n++)
                    Cp[(size_t)token * 1024 + (bn0 & 1023) + wc * 32 + n * 16 + fr] =
                        f2bf(f * acc[m][n][r]);
                if (wc == 0 && fr == 0) {
                    float xn = f * f * n2;
                    ns[hh * 2048 + token] = xn;
                    float op = 1.f + e;
                    float sech2 = 4.f * e / (op * op);   // 1 - tanh^2(u)
                    ds[hh * 2048 + token] = (n2 < 1e-6f) ? (1.f - c * xn) : sech2;
                }
            }
    }
}

// ---------------- bf16 MFMA GEMM, 64x64 tile (r17-verified) — out-GEMM ----------------
__global__ __launch_bounds__(256) void k_gemm64(const unsigned short* __restrict__ A,
                                                const unsigned short* __restrict__ B,
                                                float* __restrict__ C,
                                                int M, int N, int K) {
    __shared__ __align__(16) unsigned short As[64 * 32];
    __shared__ __align__(16) unsigned short Bs[64 * 32];
    const int tid  = threadIdx.x;
    const int lane = tid & 63;
    const int w    = tid >> 6;
    const int wr   = w >> 1, wc = w & 1;
    const int fr   = lane & 15;
    const int fg   = lane >> 4;
    const int nbx  = N >> 6;
    const int bx   = blockIdx.x % nbx;
    const int by   = blockIdx.x / nbx;
    const int bm0  = by * 64, bn0 = bx * 64;

    const int lrow = lane >> 2;
    const int lcol = (lane & 3) * 8;

    f32x4 acc[2][2] = {};

    for (int kk = 0; kk < K; kk += 32) {
#ifdef HAVE_GLL
        {
            const unsigned short* gp0 = &A[(size_t)(bm0 + w * 16 + lrow) * K + kk + lcol];
            __builtin_amdgcn_global_load_lds((const __attribute__((address_space(1))) void*)gp0,
                (__attribute__((address_space(3))) void*)&As[(w * 16) * 32], 16, 0, 0);
            const unsigned short* gp1 = &B[(size_t)(bn0 + w * 16 + lrow) * K + kk + lcol];
            __builtin_amdgcn_global_load_lds((const __attribute__((address_space(1))) void*)gp1,
                (__attribute__((address_space(3))) void*)&Bs[(w * 16) * 32], 16, 0, 0);
        }
#else
        {
            uint4 a0 = *(const uint4*)&A[(size_t)(bm0 + w * 16 + lrow) * K + kk + lcol];
            uint4 b0 = *(const uint4*)&B[(size_t)(bn0 + w * 16 + lrow) * K + kk + lcol];
            *(uint4*)&As[(w * 16 + lrow) * 32 + lcol] = a0;
            *(uint4*)&Bs[(w * 16 + lrow) * 32 + lcol] = b0;
        }
#endif
        __syncthreads();

        bf16x8 av[2], bv[2];
#pragma unroll
        for (int m = 0; m < 2; m++)
            av[m] = *(const bf16x8*)&As[(wr * 32 + m * 16 + fr) * 32 + fg * 8];
#pragma unroll
        for (int n = 0; n < 2; n++)
            bv[n] = *(const bf16x8*)&Bs[(wc * 32 + n * 16 + fr) * 32 + fg * 8];
#pragma unroll
        for (int m = 0; m < 2; m++)
#pragma unroll
            for (int n = 0; n < 2; n++)
                acc[m][n] = __builtin_amdgcn_mfma_f32_16x16x32_bf16(av[m], bv[n], acc[m][n], 0, 0, 0);
        __syncthreads();
    }

    const int crow0 = bm0 + wr * 32 + fg * 4;
#pragma unroll
    for (int m = 0; m < 2; m++)
#pragma unroll
        for (int n = 0; n < 2; n++)
#pragma unroll
            for (int r = 0; r < 4; r++)
                C[(size_t)(crow0 + m * 16 + r) * N + bn0 + wc * 32 + n * 16 + fr] =
                    acc[m][n][r];
}

// ---------------- MFMA flash attention v6 (r13-verified, unchanged) ----------------
__global__ __launch_bounds__(256) void k_attn_part(const unsigned short* __restrict__ Qb,
                                                   const unsigned short* __restrict__ Kb,
                                                   const unsigned short* __restrict__ Vtg,
                                                   const float* __restrict__ xns,
                                                   const float* __restrict__ xds,
                                                   const float* __restrict__ yns,
                                                   const float* __restrict__ yds,
                                                   const float* __restrict__ pLogC,
                                                   const float* __restrict__ pBeta,
                                                   unsigned short* __restrict__ Og,
                                                   float* __restrict__ ml,
                                                   unsigned short* __restrict__ conc) {
    __shared__ __align__(16) unsigned short Ks[64][72];
    __shared__ __align__(16) unsigned short Vt[64][72];
    __shared__ __align__(16) float yl[64];    // holds 2c * yn
    __shared__ __align__(16) float ydl[64];   // raw yds

    const float c      = softplus_f(pLogC[0]);
    const float sc     = sqrtf(c);
    const float inv_sc = 1.f / sc;
    const float bpos   = softplus_f(pBeta[0]);
    const float b2     = bpos * inv_sc;     // log2-domain score scale
    const float twoc   = 2.f * c;
    const float m4c    = -4.f * c;

    const int b = 2303 - blockIdx.x;        // heavy (large qt) dispatch first
    const int h = b / 144;
    const int t = b % 144;
    const int a = (t >= 4) + (t >= 12) + (t >= 24) + (t >= 40) + (t >= 60) + (t >= 84) + (t >= 112);
    const int r0_ = t - 2 * a * (a + 1);
    const int nch = a + 1;
    const int qt  = 4 * a + r0_ / nch;
    const int ci  = r0_ - (r0_ / nch) * nch;
    const int jt0 = ci * (qt + 1) / nch;
    const int jt1 = (ci + 1) * (qt + 1) / nch;
    const int q0  = qt << 6;
    const int slot = b;
    const bool full = (a == 0);

    const int tid  = threadIdx.x;
    const int lane = tid & 63;
    const int w    = tid >> 6;
    const int wq0  = w * 16;
    const int fr   = lane & 15;
    const int fg   = lane >> 4;
    const int rS   = tid >> 3;
    const int cS   = (tid & 7) * 8;

    const int qglob = q0 + wq0 + fr;          // this lane's q row (global)
    const float xi2 = twoc * xns[h * 2048 + qglob];
    const float dxr = xds[h * 2048 + qglob];

    // Q fragment in registers (wave-private rows; no LDS)
    const unsigned short* qp = &Qb[(size_t)qglob * 1024 + h * 64 + fg * 8];
    const bf16x8 qb0 = *(const bf16x8*)qp;
    const bf16x8 qb1 = *(const bf16x8*)(qp + 32);

    float lrow = 0.f;                         // lane-local partial row sum
    f32x4 acc[4] = {};

    uint4 kr0, kr1, vr0, vr1;
    float ylr = 0.f;
#define LOAD_TILE(jtv) do { int kb = (jtv) << 6; \
    kr0 = *(const uint4*)&Kb[(size_t)(kb + rS) * 1024 + h * 64 + cS]; \
    kr1 = *(const uint4*)&Kb[(size_t)(kb + 32 + rS) * 1024 + h * 64 + cS]; \
    vr0 = *(const uint4*)&Vtg[(size_t)(h * 64 + rS) * 2048 + kb + cS]; \
    vr1 = *(const uint4*)&Vtg[(size_t)(h * 64 + 32 + rS) * 2048 + kb + cS]; \
    if (tid < 64) ylr = yns[h * 2048 + kb + tid]; \
    else if (tid < 128) ylr = yds[h * 2048 + kb + tid - 64]; \
} while (0)

// score transform -> p = exp2(s); all 4 transcendentals single HW instrs
#define XFORM(DOMASK) do { \
    _Pragma("unroll") for (int tn = 0; tn < 4; tn++) { \
        float4 yv  = *(const float4*)&yl[tn * 16 + fg * 4];   /* 2c*yn */ \
        float4 ydv = *(const float4*)&ydl[tn * 16 + fg * 4]; \
        _Pragma("unroll") for (int r = 0; r < 4; r++) { \
            float diff2 = fmaf(st[tn][r], m4c, xi2 + (&yv.x)[r]); \
            float den   = fmaxf(dxr * (&ydv.x)[r], EPSF); \
            float tt    = fmaxf(diff2 * rcp_f(den), EPSF); \
            float wv    = 1.f + tt + sqrt_f(tt * (tt + 2.f)); \
            float sv    = -b2 * log2_f(wv); \
            if (DOMASK && (k0 + tn * 16 + fg * 4 + r > qglob)) sv = -3.0e38f; \
            p[tn][r] = exp2_f(sv);           /* masked -> +0 */ \
        } \
    } \
} while (0)

    LOAD_TILE(jt0);
    for (int jt = jt0; jt < jt1; ++jt) {
        const int k0 = jt << 6;
        __syncthreads();
        *(uint4*)&Ks[rS][cS]      = kr0;
        *(uint4*)&Ks[32 + rS][cS] = kr1;
        *(uint4*)&Vt[rS][cS]      = vr0;
        *(uint4*)&Vt[32 + rS][cS] = vr1;
        if (tid < 64)       yl[tid]       = twoc * ylr;
        else if (tid < 128) ydl[tid - 64] = ylr;
        __syncthreads();
        if (jt + 1 < jt1) LOAD_TILE(jt + 1);

        // ---- S^T = K Q^T via MFMA (A = K rows, B = Q regs) ----
        f32x4 st[4] = {};
#pragma unroll
        for (int tn = 0; tn < 4; tn++) {
            bf16x8 ka0 = *(const bf16x8*)&Ks[tn * 16 + fr][fg * 8];
            bf16x8 ka1 = *(const bf16x8*)&Ks[tn * 16 + fr][32 + fg * 8];
            st[tn] = __builtin_amdgcn_mfma_f32_16x16x32_bf16(ka0, qb0, st[tn], 0, 0, 0);
            st[tn] = __builtin_amdgcn_mfma_f32_16x16x32_bf16(ka1, qb1, st[tn], 0, 0, 0);
        }

        // ---- transform + exp2 (bounded scores: m = 0, r12-verified) ----
        float p[4][4];
        if (jt == qt) XFORM(1); else XFORM(0);

        // ---- lane-local row-sum accumulation ----
        {
            float r0 = (p[0][0] + p[0][1]) + (p[0][2] + p[0][3]);
            float r1 = (p[1][0] + p[1][1]) + (p[1][2] + p[1][3]);
            float r2 = (p[2][0] + p[2][1]) + (p[2][2] + p[2][3]);
            float r3 = (p[3][0] + p[3][1]) + (p[3][2] + p[3][3]);
            lrow += (r0 + r1) + (r2 + r3);
        }

        // ---- pack P + assemble PV A-frags via bpermute (verified r10) ----
        int lo[4], hi[4];
#pragma unroll
        for (int tn = 0; tn < 4; tn++) {
            lo[tn] = cvt_pk_bf16(p[tn][0], p[tn][1]);
            hi[tn] = cvt_pk_bf16(p[tn][2], p[tn][3]);
        }
        const int adrA = (fr + ((fg & 1) << 5)) << 2;
        const int adrB = adrA + 64;
        const bool hiSel = (fg >= 2);
        union PU { int i[4]; bf16x8 v; };
        PU pu0, pu1;
#pragma unroll
        for (int kh = 0; kh < 2; kh++) {
            int l0 = bperm(adrA, lo[2 * kh]);
            int l1 = bperm(adrA, lo[2 * kh + 1]);
            int h0 = bperm(adrA, hi[2 * kh]);
            int h1 = bperm(adrA, hi[2 * kh + 1]);
            int l0b = bperm(adrB, lo[2 * kh]);
            int l1b = bperm(adrB, lo[2 * kh + 1]);
            int h0b = bperm(adrB, hi[2 * kh]);
            int h1b = bperm(adrB, hi[2 * kh + 1]);
            PU& pu = kh ? pu1 : pu0;
            pu.i[0] = hiSel ? l1 : l0;
            pu.i[1] = hiSel ? h1 : h0;
            pu.i[2] = hiSel ? l1b : l0b;
            pu.i[3] = hiSel ? h1b : h0b;
        }
        bf16x8 pa0 = pu0.v, pa1 = pu1.v;

        // ---- acc += P V via MFMA ----
#pragma unroll
        for (int tn = 0; tn < 4; tn++) {
            bf16x8 vb0 = *(const bf16x8*)&Vt[tn * 16 + fr][fg * 8];
            bf16x8 vb1 = *(const bf16x8*)&Vt[tn * 16 + fr][32 + fg * 8];
            acc[tn] = __builtin_amdgcn_mfma_f32_16x16x32_bf16(pa0, vb0, acc[tn], 0, 0, 0);
            acc[tn] = __builtin_amdgcn_mfma_f32_16x16x32_bf16(pa1, vb1, acc[tn], 0, 0, 0);
        }
    }
#undef LOAD_TILE
#undef XFORM

    // ---- one cross-lane reduce for the row sums ----
    lrow += __shfl_xor(lrow, 16);
    lrow += __shfl_xor(lrow, 32);      // lanes with same fr now hold row-total l

    if (full) {
        float lr[4];
#pragma unroll
        for (int r = 0; r < 4; r++) lr[r] = bpermf((fg * 4 + r) << 2, lrow);
#pragma unroll
        for (int r = 0; r < 4; r++) {
            float rl = 1.f / lr[r];
            float tvv[4];
            float n2 = 0.f;
#pragma unroll
            for (int tn = 0; tn < 4; tn++) { tvv[tn] = acc[tn][r] * rl; n2 += tvv[tn] * tvv[tn]; }
#pragma unroll
            for (int o = 1; o < 16; o <<= 1) n2 += __shfl_xor(n2, o);
            float nt   = fmaxf(sqrtf(n2), EPSF);
            float f1   = tanhf(sc * nt) / (sc * nt);
            float ny   = fmaxf(f1 * sqrtf(n2), EPSF);
            float ncl  = fminf(ny, inv_sc - EPSF);
            float coef = atanhf(sc * ncl) / (sc * ny);
            int row = q0 + wq0 + fg * 4 + r;
#pragma unroll
            for (int tn = 0; tn < 4; tn++)
                conc[(size_t)row * 1024 + h * 64 + tn * 16 + fr] = f2bf(coef * f1 * tvv[tn]);
        }
    } else {
        if (fg == 0)
            ml[(size_t)slot * 64 + wq0 + fr] = lrow;   // l only (m == 0 constant)
#pragma unroll
        for (int r = 0; r < 4; r++) {
            int row = wq0 + fg * 4 + r;
#pragma unroll
            for (int tn = 0; tn < 4; tn++)
                Og[(size_t)slot * 4096 + row * 64 + tn * 16 + fr] = f2bf(acc[tn][r]);
        }
    }
}

// ---------------- merge partials (plain sums; m == 0) + exp/log-map epilogue (r13) ----------------
__global__ __launch_bounds__(256) void k_merge(const unsigned short* __restrict__ Og,
                                               const float* __restrict__ ml,
                                               const float* __restrict__ pLogC,
                                               unsigned short* __restrict__ conc) {
    const float c      = softplus_f(pLogC[0]);
    const float sc     = sqrtf(c);
    const float inv_sc = 1.f / sc;
    int gid2 = (blockIdx.x * 256 + threadIdx.x) >> 6;   // 0..28671
    int lane = threadIdx.x & 63;
    int h = gid2 / 1792;
    int i = 256 + (gid2 - h * 1792);                    // rows with qt >= 4
    int qt = i >> 6, row = i & 63;
    int a = qt >> 2;
    int nch = a + 1;
    int slot0 = h * 144 + 2 * a * (a + 1) + (qt & 3) * (a + 1);

    float L = 0.f, O = 0.f;
    for (int k = 0; k < nch; k++) {
        L += ml[(size_t)(slot0 + k) * 64 + row];
        O += bf2f(Og[(size_t)(slot0 + k) * 4096 + row * 64 + lane]);
    }
    float tv = O / L;
    float n2 = tv * tv;
#pragma unroll
    for (int o = 1; o < 64; o <<= 1) n2 += __shfl_xor(n2, o);
    float nt   = fmaxf(sqrtf(n2), EPSF);
    float f1   = tanhf(sc * nt) / (sc * nt);
    float ny   = fmaxf(f1 * sqrtf(n2), EPSF);
    float ncl  = fminf(ny, inv_sc - EPSF);
    float coef = atanhf(sc * ncl) / (sc * ny);
    conc[(size_t)i * 1024 + h * 64 + lane] = f2bf(coef * f1 * tv);
}

// ---------------- launch (r19 pipeline; QKV GEMM retiled to 64x64, 6 blocks/CU) ----------------
// ws layout (peak < 37.2 MB; proven zone):
//   0-4: Vtg (transposed by QKV GEMM) | 4-8: Qtb (mapped) | 8-12: Ktb (mapped)
//   12-16: concb | 16-16.5: xns/yns/xds/yds | 16.5-18.5: wob | 18.5-22.5: xb
//   22.5-28.5: wqb|wkb|wvb | 18.5-36.5: Og (reuses dead xb/w*) | 36.5-37.1: ml
extern "C" void kernel_launch(void* const* d_in, const int* in_sizes, int n_in,
                              void* d_out, int out_size, void* d_ws, size_t ws_size,
                              hipStream_t stream) {
    const float* x     = (const float*)d_in[0];
    const float* Wq    = (const float*)d_in[1];
    const float* Wk    = (const float*)d_in[2];
    const float* Wv    = (const float*)d_in[3];
    const float* Wo    = (const float*)d_in[4];
    const float* pLogC = (const float*)d_in[5];
    const float* pBeta = (const float*)d_in[6];
    float* out = (float*)d_out;

    char* w = (char*)d_ws;
    unsigned short* Vtg   = (unsigned short*)(w);
    unsigned short* Qtb   = (unsigned short*)(w + (4u  << 20));
    unsigned short* Ktb   = (unsigned short*)(w + (8u  << 20));
    unsigned short* concb = (unsigned short*)(w + (12u << 20));
    float*          xns   = (float*)(w + (16u << 20));
    float*          yns   = (float*)(w + (16u << 20) + (1u << 17));
    float*          xds   = (float*)(w + (16u << 20) + (2u << 17));
    float*          yds   = (float*)(w + (16u << 20) + (3u << 17));
    unsigned short* wob   = (unsigned short*)(w + (16u << 20) + (1u << 19));
    unsigned short* xb    = (unsigned short*)(w + (18u << 20) + (1u << 19));
    unsigned short* wqb   = (unsigned short*)(w + (22u << 20) + (1u << 19));
    unsigned short* wkb   = (unsigned short*)(w + (24u << 20) + (1u << 19));
    unsigned short* wvb   = (unsigned short*)(w + (26u << 20) + (1u << 19));
    unsigned short* Og    = (unsigned short*)(w + (18u << 20) + (1u << 19));
    float*          ml    = (float*)(w + (36u << 20) + (1u << 19));

    k_f2b_all<<<2048, 256, 0, stream>>>(x, Wq, Wk, Wv, Wo, xb, wqb, wkb, wvb, wob);

    // fused QKV projection + exp_map + transposed V: 64x64 tiles, 1536 blocks = 6/CU
    k_gemm_qkv<<<1536, 256, 0, stream>>>(xb, wqb, Qtb, Ktb, Vtg,
                                         xns, xds, yns, yds, pLogC,
                                         2048, 3072, 1024);

    k_attn_part<<<2304, 256, 0, stream>>>(Qtb, Ktb, Vtg, xns, xds, yns, yds,
                                          pLogC, pBeta, Og, ml, concb);

    k_merge<<<7168, 256, 0, stream>>>(Og, ml, pLogC, concb);

    // output GEMM: 64x64 tiles, grid 512 = 2 blocks/CU (r17-verified)
    k_gemm64<<<512, 256, 0, stream>>>(concb, wob, out, 2048, 1024, 1024);
}

// Round 21
// 121.326 us; speedup vs baseline: 1.0253x; 1.0253x over previous
//
#include <hip/hip_runtime.h>
#include <stdint.h>

#define EPSF 1e-5f

typedef float f32x4 __attribute__((ext_vector_type(4)));
typedef short bf16x8 __attribute__((ext_vector_type(8)));   // 8 bf16 in 4 VGPRs

__device__ __forceinline__ float softplus_f(float x) {
    return x > 20.f ? x : log1pf(expf(x));
}

// fp32 -> bf16 RNE (finite inputs)
__device__ __forceinline__ unsigned short f2bf(float f) {
    union { float f; unsigned int u; } v; v.f = f;
    unsigned int r = v.u + 0x7FFFu + ((v.u >> 16) & 1u);
    return (unsigned short)(r >> 16);
}
__device__ __forceinline__ float bf2f(unsigned short u) {
    union { unsigned int i; float f; } v; v.i = ((unsigned int)u) << 16;
    return v.f;
}
__device__ __forceinline__ int cvt_pk_bf16(float a, float b) {
    int d;
    asm("v_cvt_pk_bf16_f32 %0, %1, %2" : "=v"(d) : "v"(a), "v"(b));
    return d;
}
__device__ __forceinline__ int bperm(int byte_addr, int v) {
    return __builtin_amdgcn_ds_bpermute(byte_addr, v);
}
__device__ __forceinline__ float bpermf(int byte_addr, float v) {
    return __int_as_float(__builtin_amdgcn_ds_bpermute(byte_addr, __float_as_int(v)));
}
// single-instruction HW transcendentals (~1 ulp)
__device__ __forceinline__ float rcp_f(float x)  { float d; asm("v_rcp_f32 %0, %1"  : "=v"(d) : "v"(x)); return d; }
__device__ __forceinline__ float sqrt_f(float x) { float d; asm("v_sqrt_f32 %0, %1" : "=v"(d) : "v"(x)); return d; }
__device__ __forceinline__ float log2_f(float x) { float d; asm("v_log_f32 %0, %1"  : "=v"(d) : "v"(x)); return d; }
__device__ __forceinline__ float exp2_f(float x) { float d; asm("v_exp_f32 %0, %1"  : "=v"(d) : "v"(x)); return d; }

// ---------------- fused fp32 -> bf16 convert, float4-vectorized (r13) ----------------
__global__ __launch_bounds__(256) void k_f2b_all(const float* __restrict__ x,
                                                 const float* __restrict__ W0, const float* __restrict__ W1,
                                                 const float* __restrict__ W2, const float* __restrict__ W3,
                                                 unsigned short* __restrict__ xb,
                                                 unsigned short* __restrict__ o0, unsigned short* __restrict__ o1,
                                                 unsigned short* __restrict__ o2, unsigned short* __restrict__ o3) {
    const int NX4 = 524288;
    const int NW4 = 262144;
    int i = blockIdx.x * 256 + threadIdx.x;
    int stride = gridDim.x * 256;
    for (; i < NX4 + 4 * NW4; i += stride) {
        const float4* src;
        ushort4* dst;
        if (i < NX4) {
            src = (const float4*)x + i;
            dst = (ushort4*)xb + i;
        } else {
            int j = i - NX4;
            int sel = j >> 18, off = j & (NW4 - 1);
            const float* s = sel == 0 ? W0 : sel == 1 ? W1 : sel == 2 ? W2 : W3;
            unsigned short* d = sel == 0 ? o0 : sel == 1 ? o1 : sel == 2 ? o2 : o3;
            src = (const float4*)s + off;
            dst = (ushort4*)d + off;
        }
        float4 v = *src;
        ushort4 o;
        o.x = f2bf(v.x); o.y = f2bf(v.y); o.z = f2bf(v.z); o.w = f2bf(v.w);
        *dst = o;
    }
}

#if defined(__has_builtin)
#if __has_builtin(__builtin_amdgcn_global_load_lds)
#define HAVE_GLL 1
#endif
#endif

// ---------------- bf16 MFMA GEMM, 128x64 tile + FUSED exp_map epilogue (r19-verified) ----------------
// B = [3072][K] concat. Each output tile = ONE head (64 cols) x 128 tokens:
//   sel==0/1 (Q/K): per-token row norm in-epilogue (shfl over fr lanes + 1KB LDS
//   cross-wave combine + one barrier), exp_map applied, MAPPED bf16 + ns/ds written.
//   sel==2 (V): transposed store into Vtg (r18-verified).
__global__ __launch_bounds__(256) void k_gemm_qkv(const unsigned short* __restrict__ A,
                                                  const unsigned short* __restrict__ B,
                                                  unsigned short* __restrict__ Qo,
                                                  unsigned short* __restrict__ Ko,
                                                  unsigned short* __restrict__ Vtg,
                                                  float* __restrict__ xns, float* __restrict__ xds,
                                                  float* __restrict__ yns, float* __restrict__ yds,
                                                  const float* __restrict__ pLogC,
                                                  int M, int N, int K) {
    __shared__ __align__(16) unsigned short As[128 * 32];
    __shared__ __align__(16) unsigned short Bs[64 * 32];
    const int tid  = threadIdx.x;
    const int lane = tid & 63;
    const int w    = tid >> 6;
    const int wr   = w >> 1, wc = w & 1;
    const int fr   = lane & 15;
    const int fg   = lane >> 4;
    const int nbx  = N >> 6;
    const int bx   = blockIdx.x % nbx;
    const int by   = blockIdx.x / nbx;
    const int bm0  = by * 128, bn0 = bx * 64;

    const int lrow = lane >> 2;
    const int lcol = (lane & 3) * 8;

    f32x4 acc[4][2] = {};

    for (int kk = 0; kk < K; kk += 32) {
#ifdef HAVE_GLL
        {
            const unsigned short* gp0 = &A[(size_t)(bm0 + w * 16 + lrow) * K + kk + lcol];
            __builtin_amdgcn_global_load_lds((const __attribute__((address_space(1))) void*)gp0,
                (__attribute__((address_space(3))) void*)&As[(w * 16) * 32], 16, 0, 0);
            const unsigned short* gp1 = &A[(size_t)(bm0 + 64 + w * 16 + lrow) * K + kk + lcol];
            __builtin_amdgcn_global_load_lds((const __attribute__((address_space(1))) void*)gp1,
                (__attribute__((address_space(3))) void*)&As[(64 + w * 16) * 32], 16, 0, 0);
            const unsigned short* gp2 = &B[(size_t)(bn0 + w * 16 + lrow) * K + kk + lcol];
            __builtin_amdgcn_global_load_lds((const __attribute__((address_space(1))) void*)gp2,
                (__attribute__((address_space(3))) void*)&Bs[(w * 16) * 32], 16, 0, 0);
        }
#else
        {
            uint4 a0 = *(const uint4*)&A[(size_t)(bm0 + w * 16 + lrow) * K + kk + lcol];
            uint4 a1 = *(const uint4*)&A[(size_t)(bm0 + 64 + w * 16 + lrow) * K + kk + lcol];
            uint4 b0 = *(const uint4*)&B[(size_t)(bn0 + w * 16 + lrow) * K + kk + lcol];
            *(uint4*)&As[(w * 16 + lrow) * 32 + lcol]      = a0;
            *(uint4*)&As[(64 + w * 16 + lrow) * 32 + lcol] = a1;
            *(uint4*)&Bs[(w * 16 + lrow) * 32 + lcol]      = b0;
        }
#endif
        __syncthreads();

        bf16x8 av[4], bv[2];
#pragma unroll
        for (int m = 0; m < 4; m++)
            av[m] = *(const bf16x8*)&As[(wr * 64 + m * 16 + fr) * 32 + fg * 8];
#pragma unroll
        for (int n = 0; n < 2; n++)
            bv[n] = *(const bf16x8*)&Bs[(wc * 32 + n * 16 + fr) * 32 + fg * 8];
#pragma unroll
        for (int m = 0; m < 4; m++)
#pragma unroll
            for (int n = 0; n < 2; n++)
                acc[m][n] = __builtin_amdgcn_mfma_f32_16x16x32_bf16(av[m], bv[n], acc[m][n], 0, 0, 0);
        __syncthreads();
    }

    const int crow0 = bm0 + wr * 64 + fg * 4;
    const int sel = bn0 >> 10;
    if (sel == 2) {
        // V tile: transposed store (r18-verified)
        const int col0 = (bn0 & 1023) + wc * 32 + fr;
#pragma unroll
        for (int m = 0; m < 4; m++)
#pragma unroll
            for (int n = 0; n < 2; n++) {
                ushort4 o;
                o.x = f2bf(acc[m][n][0]); o.y = f2bf(acc[m][n][1]);
                o.z = f2bf(acc[m][n][2]); o.w = f2bf(acc[m][n][3]);
                *(ushort4*)&Vtg[(size_t)(col0 + n * 16) * 2048 + crow0 + m * 16] = o;
            }
    } else {
        // Q/K tile: fused exp_map (tile = one head x 128 tokens)
        const float c  = softplus_f(pLogC[0]);
        const float sc = sqrtf(c);
        float* ns = sel == 0 ? xns : yns;
        float* ds = sel == 0 ? xds : yds;
        unsigned short* Cp = sel == 0 ? Qo : Ko;
        const int hh  = (bn0 & 1023) >> 6;

        // per-(m,r) partial: sum of squares over this wave's 32 cols
        float ps[4][4];
#pragma unroll
        for (int m = 0; m < 4; m++)
#pragma unroll
            for (int r = 0; r < 4; r++) {
                float s = acc[m][0][r] * acc[m][0][r] + acc[m][1][r] * acc[m][1][r];
#pragma unroll
                for (int o = 1; o < 16; o <<= 1) s += __shfl_xor(s, o);
                ps[m][r] = s;
            }
        // cross-wave (wc) combine via reused As LDS: part[(wr*2+wc)*64 + localrow]
        float* part = (float*)As;
        if (fr == 0)
#pragma unroll
            for (int m = 0; m < 4; m++)
#pragma unroll
                for (int r = 0; r < 4; r++)
                    part[(wr * 2 + wc) * 64 + fg * 4 + m * 16 + r] = ps[m][r];
        __syncthreads();

#pragma unroll
        for (int m = 0; m < 4; m++)
#pragma unroll
            for (int r = 0; r < 4; r++) {
                int lr_ = fg * 4 + m * 16 + r;
                float n2 = part[(wr * 2) * 64 + lr_] + part[(wr * 2 + 1) * 64 + lr_];
                float nn = fmaxf(sqrtf(n2), EPSF);
                float u  = sc * nn;
                float e  = __expf(-2.f * u);
                float th = (1.f - e) / (1.f + e);    // tanh(u), stable
                float f  = th / (sc * nn);
                int token = crow0 + m * 16 + r;
#pragma unroll
                for (int n = 0; n < 2; n++)
                    Cp[(size_t)token * 1024 + (bn0 & 1023) + wc * 32 + n * 16 + fr] =
                        f2bf(f * acc[m][n][r]);
                if (wc == 0 && fr == 0) {
                    float xn = f * f * n2;
                    ns[hh * 2048 + token] = xn;
                    float op = 1.f + e;
                    float sech2 = 4.f * e / (op * op);   // 1 - tanh^2(u)
                    ds[hh * 2048 + token] = (n2 < 1e-6f) ? (1.f - c * xn) : sech2;
                }
            }
    }
}

// ---------------- bf16 MFMA GEMM, 64x64 tile (r17-verified) — out-GEMM ----------------
__global__ __launch_bounds__(256) void k_gemm64(const unsigned short* __restrict__ A,
                                                const unsigned short* __restrict__ B,
                                                float* __restrict__ C,
                                                int M, int N, int K) {
    __shared__ __align__(16) unsigned short As[64 * 32];
    __shared__ __align__(16) unsigned short Bs[64 * 32];
    const int tid  = threadIdx.x;
    const int lane = tid & 63;
    const int w    = tid >> 6;
    const int wr   = w >> 1, wc = w & 1;
    const int fr   = lane & 15;
    const int fg   = lane >> 4;
    const int nbx  = N >> 6;
    const int bx   = blockIdx.x % nbx;
    const int by   = blockIdx.x / nbx;
    const int bm0  = by * 64, bn0 = bx * 64;

    const int lrow = lane >> 2;
    const int lcol = (lane & 3) * 8;

    f32x4 acc[2][2] = {};

    for (int kk = 0; kk < K; kk += 32) {
#ifdef HAVE_GLL
        {
            const unsigned short* gp0 = &A[(size_t)(bm0 + w * 16 + lrow) * K + kk + lcol];
            __builtin_amdgcn_global_load_lds((const __attribute__((address_space(1))) void*)gp0,
                (__attribute__((address_space(3))) void*)&As[(w * 16) * 32], 16, 0, 0);
            const unsigned short* gp1 = &B[(size_t)(bn0 + w * 16 + lrow) * K + kk + lcol];
            __builtin_amdgcn_global_load_lds((const __attribute__((address_space(1))) void*)gp1,
                (__attribute__((address_space(3))) void*)&Bs[(w * 16) * 32], 16, 0, 0);
        }
#else
        {
            uint4 a0 = *(const uint4*)&A[(size_t)(bm0 + w * 16 + lrow) * K + kk + lcol];
            uint4 b0 = *(const uint4*)&B[(size_t)(bn0 + w * 16 + lrow) * K + kk + lcol];
            *(uint4*)&As[(w * 16 + lrow) * 32 + lcol] = a0;
            *(uint4*)&Bs[(w * 16 + lrow) * 32 + lcol] = b0;
        }
#endif
        __syncthreads();

        bf16x8 av[2], bv[2];
#pragma unroll
        for (int m = 0; m < 2; m++)
            av[m] = *(const bf16x8*)&As[(wr * 32 + m * 16 + fr) * 32 + fg * 8];
#pragma unroll
        for (int n = 0; n < 2; n++)
            bv[n] = *(const bf16x8*)&Bs[(wc * 32 + n * 16 + fr) * 32 + fg * 8];
#pragma unroll
        for (int m = 0; m < 2; m++)
#pragma unroll
            for (int n = 0; n < 2; n++)
                acc[m][n] = __builtin_amdgcn_mfma_f32_16x16x32_bf16(av[m], bv[n], acc[m][n], 0, 0, 0);
        __syncthreads();
    }

    const int crow0 = bm0 + wr * 32 + fg * 4;
#pragma unroll
    for (int m = 0; m < 2; m++)
#pragma unroll
        for (int n = 0; n < 2; n++)
#pragma unroll
            for (int r = 0; r < 4; r++)
                C[(size_t)(crow0 + m * 16 + r) * N + bn0 + wc * 32 + n * 16 + fr] =
                    acc[m][n][r];
}

// ---------------- MFMA flash attention v6 (r13-verified, unchanged) ----------------
__global__ __launch_bounds__(256) void k_attn_part(const unsigned short* __restrict__ Qb,
                                                   const unsigned short* __restrict__ Kb,
                                                   const unsigned short* __restrict__ Vtg,
                                                   const float* __restrict__ xns,
                                                   const float* __restrict__ xds,
                                                   const float* __restrict__ yns,
                                                   const float* __restrict__ yds,
                                                   const float* __restrict__ pLogC,
                                                   const float* __restrict__ pBeta,
                                                   unsigned short* __restrict__ Og,
                                                   float* __restrict__ ml,
                                                   unsigned short* __restrict__ conc) {
    __shared__ __align__(16) unsigned short Ks[64][72];
    __shared__ __align__(16) unsigned short Vt[64][72];
    __shared__ __align__(16) float yl[64];    // holds 2c * yn
    __shared__ __align__(16) float ydl[64];   // raw yds

    const float c      = softplus_f(pLogC[0]);
    const float sc     = sqrtf(c);
    const float inv_sc = 1.f / sc;
    const float bpos   = softplus_f(pBeta[0]);
    const float b2     = bpos * inv_sc;     // log2-domain score scale
    const float twoc   = 2.f * c;
    const float m4c    = -4.f * c;

    const int b = 2303 - blockIdx.x;        // heavy (large qt) dispatch first
    const int h = b / 144;
    const int t = b % 144;
    const int a = (t >= 4) + (t >= 12) + (t >= 24) + (t >= 40) + (t >= 60) + (t >= 84) + (t >= 112);
    const int r0_ = t - 2 * a * (a + 1);
    const int nch = a + 1;
    const int qt  = 4 * a + r0_ / nch;
    const int ci  = r0_ - (r0_ / nch) * nch;
    const int jt0 = ci * (qt + 1) / nch;
    const int jt1 = (ci + 1) * (qt + 1) / nch;
    const int q0  = qt << 6;
    const int slot = b;
    const bool full = (a == 0);

    const int tid  = threadIdx.x;
    const int lane = tid & 63;
    const int w    = tid >> 6;
    const int wq0  = w * 16;
    const int fr   = lane & 15;
    const int fg   = lane >> 4;
    const int rS   = tid >> 3;
    const int cS   = (tid & 7) * 8;

    const int qglob = q0 + wq0 + fr;          // this lane's q row (global)
    const float xi2 = twoc * xns[h * 2048 + qglob];
    const float dxr = xds[h * 2048 + qglob];

    // Q fragment in registers (wave-private rows; no LDS)
    const unsigned short* qp = &Qb[(size_t)qglob * 1024 + h * 64 + fg * 8];
    const bf16x8 qb0 = *(const bf16x8*)qp;
    const bf16x8 qb1 = *(const bf16x8*)(qp + 32);

    float lrow = 0.f;                         // lane-local partial row sum
    f32x4 acc[4] = {};

    uint4 kr0, kr1, vr0, vr1;
    float ylr = 0.f;
#define LOAD_TILE(jtv) do { int kb = (jtv) << 6; \
    kr0 = *(const uint4*)&Kb[(size_t)(kb + rS) * 1024 + h * 64 + cS]; \
    kr1 = *(const uint4*)&Kb[(size_t)(kb + 32 + rS) * 1024 + h * 64 + cS]; \
    vr0 = *(const uint4*)&Vtg[(size_t)(h * 64 + rS) * 2048 + kb + cS]; \
    vr1 = *(const uint4*)&Vtg[(size_t)(h * 64 + 32 + rS) * 2048 + kb + cS]; \
    if (tid < 64) ylr = yns[h * 2048 + kb + tid]; \
    else if (tid < 128) ylr = yds[h * 2048 + kb + tid - 64]; \
} while (0)

// score transform -> p = exp2(s); all 4 transcendentals single HW instrs
#define XFORM(DOMASK) do { \
    _Pragma("unroll") for (int tn = 0; tn < 4; tn++) { \
        float4 yv  = *(const float4*)&yl[tn * 16 + fg * 4];   /* 2c*yn */ \
        float4 ydv = *(const float4*)&ydl[tn * 16 + fg * 4]; \
        _Pragma("unroll") for (int r = 0; r < 4; r++) { \
            float diff2 = fmaf(st[tn][r], m4c, xi2 + (&yv.x)[r]); \
            float den   = fmaxf(dxr * (&ydv.x)[r], EPSF); \
            float tt    = fmaxf(diff2 * rcp_f(den), EPSF); \
            float wv    = 1.f + tt + sqrt_f(tt * (tt + 2.f)); \
            float sv    = -b2 * log2_f(wv); \
            if (DOMASK && (k0 + tn * 16 + fg * 4 + r > qglob)) sv = -3.0e38f; \
            p[tn][r] = exp2_f(sv);           /* masked -> +0 */ \
        } \
    } \
} while (0)

    LOAD_TILE(jt0);
    for (int jt = jt0; jt < jt1; ++jt) {
        const int k0 = jt << 6;
        __syncthreads();
        *(uint4*)&Ks[rS][cS]      = kr0;
        *(uint4*)&Ks[32 + rS][cS] = kr1;
        *(uint4*)&Vt[rS][cS]      = vr0;
        *(uint4*)&Vt[32 + rS][cS] = vr1;
        if (tid < 64)       yl[tid]       = twoc * ylr;
        else if (tid < 128) ydl[tid - 64] = ylr;
        __syncthreads();
        if (jt + 1 < jt1) LOAD_TILE(jt + 1);

        // ---- S^T = K Q^T via MFMA (A = K rows, B = Q regs) ----
        f32x4 st[4] = {};
#pragma unroll
        for (int tn = 0; tn < 4; tn++) {
            bf16x8 ka0 = *(const bf16x8*)&Ks[tn * 16 + fr][fg * 8];
            bf16x8 ka1 = *(const bf16x8*)&Ks[tn * 16 + fr][32 + fg * 8];
            st[tn] = __builtin_amdgcn_mfma_f32_16x16x32_bf16(ka0, qb0, st[tn], 0, 0, 0);
            st[tn] = __builtin_amdgcn_mfma_f32_16x16x32_bf16(ka1, qb1, st[tn], 0, 0, 0);
        }

        // ---- transform + exp2 (bounded scores: m = 0, r12-verified) ----
        float p[4][4];
        if (jt == qt) XFORM(1); else XFORM(0);

        // ---- lane-local row-sum accumulation ----
        {
            float r0 = (p[0][0] + p[0][1]) + (p[0][2] + p[0][3]);
            float r1 = (p[1][0] + p[1][1]) + (p[1][2] + p[1][3]);
            float r2 = (p[2][0] + p[2][1]) + (p[2][2] + p[2][3]);
            float r3 = (p[3][0] + p[3][1]) + (p[3][2] + p[3][3]);
            lrow += (r0 + r1) + (r2 + r3);
        }

        // ---- pack P + assemble PV A-frags via bpermute (verified r10) ----
        int lo[4], hi[4];
#pragma unroll
        for (int tn = 0; tn < 4; tn++) {
            lo[tn] = cvt_pk_bf16(p[tn][0], p[tn][1]);
            hi[tn] = cvt_pk_bf16(p[tn][2], p[tn][3]);
        }
        const int adrA = (fr + ((fg & 1) << 5)) << 2;
        const int adrB = adrA + 64;
        const bool hiSel = (fg >= 2);
        union PU { int i[4]; bf16x8 v; };
        PU pu0, pu1;
#pragma unroll
        for (int kh = 0; kh < 2; kh++) {
            int l0 = bperm(adrA, lo[2 * kh]);
            int l1 = bperm(adrA, lo[2 * kh + 1]);
            int h0 = bperm(adrA, hi[2 * kh]);
            int h1 = bperm(adrA, hi[2 * kh + 1]);
            int l0b = bperm(adrB, lo[2 * kh]);
            int l1b = bperm(adrB, lo[2 * kh + 1]);
            int h0b = bperm(adrB, hi[2 * kh]);
            int h1b = bperm(adrB, hi[2 * kh + 1]);
            PU& pu = kh ? pu1 : pu0;
            pu.i[0] = hiSel ? l1 : l0;
            pu.i[1] = hiSel ? h1 : h0;
            pu.i[2] = hiSel ? l1b : l0b;
            pu.i[3] = hiSel ? h1b : h0b;
        }
        bf16x8 pa0 = pu0.v, pa1 = pu1.v;

        // ---- acc += P V via MFMA ----
#pragma unroll
        for (int tn = 0; tn < 4; tn++) {
            bf16x8 vb0 = *(const bf16x8*)&Vt[tn * 16 + fr][fg * 8];
            bf16x8 vb1 = *(const bf16x8*)&Vt[tn * 16 + fr][32 + fg * 8];
            acc[tn] = __builtin_amdgcn_mfma_f32_16x16x32_bf16(pa0, vb0, acc[tn], 0, 0, 0);
            acc[tn] = __builtin_amdgcn_mfma_f32_16x16x32_bf16(pa1, vb1, acc[tn], 0, 0, 0);
        }
    }
#undef LOAD_TILE
#undef XFORM

    // ---- one cross-lane reduce for the row sums ----
    lrow += __shfl_xor(lrow, 16);
    lrow += __shfl_xor(lrow, 32);      // lanes with same fr now hold row-total l

    if (full) {
        float lr[4];
#pragma unroll
        for (int r = 0; r < 4; r++) lr[r] = bpermf((fg * 4 + r) << 2, lrow);
#pragma unroll
        for (int r = 0; r < 4; r++) {
            float rl = 1.f / lr[r];
            float tvv[4];
            float n2 = 0.f;
#pragma unroll
            for (int tn = 0; tn < 4; tn++) { tvv[tn] = acc[tn][r] * rl; n2 += tvv[tn] * tvv[tn]; }
#pragma unroll
            for (int o = 1; o < 16; o <<= 1) n2 += __shfl_xor(n2, o);
            float nt   = fmaxf(sqrtf(n2), EPSF);
            float f1   = tanhf(sc * nt) / (sc * nt);
            float ny   = fmaxf(f1 * sqrtf(n2), EPSF);
            float ncl  = fminf(ny, inv_sc - EPSF);
            float coef = atanhf(sc * ncl) / (sc * ny);
            int row = q0 + wq0 + fg * 4 + r;
#pragma unroll
            for (int tn = 0; tn < 4; tn++)
                conc[(size_t)row * 1024 + h * 64 + tn * 16 + fr] = f2bf(coef * f1 * tvv[tn]);
        }
    } else {
        if (fg == 0)
            ml[(size_t)slot * 64 + wq0 + fr] = lrow;   // l only (m == 0 constant)
#pragma unroll
        for (int r = 0; r < 4; r++) {
            int row = wq0 + fg * 4 + r;
#pragma unroll
            for (int tn = 0; tn < 4; tn++)
                Og[(size_t)slot * 4096 + row * 64 + tn * 16 + fr] = f2bf(acc[tn][r]);
        }
    }
}

// ---------------- merge partials (plain sums; m == 0) + exp/log-map epilogue (r13) ----------------
__global__ __launch_bounds__(256) void k_merge(const unsigned short* __restrict__ Og,
                                               const float* __restrict__ ml,
                                               const float* __restrict__ pLogC,
                                               unsigned short* __restrict__ conc) {
    const float c      = softplus_f(pLogC[0]);
    const float sc     = sqrtf(c);
    const float inv_sc = 1.f / sc;
    int gid2 = (blockIdx.x * 256 + threadIdx.x) >> 6;   // 0..28671
    int lane = threadIdx.x & 63;
    int h = gid2 / 1792;
    int i = 256 + (gid2 - h * 1792);                    // rows with qt >= 4
    int qt = i >> 6, row = i & 63;
    int a = qt >> 2;
    int nch = a + 1;
    int slot0 = h * 144 + 2 * a * (a + 1) + (qt & 3) * (a + 1);

    float L = 0.f, O = 0.f;
    for (int k = 0; k < nch; k++) {
        L += ml[(size_t)(slot0 + k) * 64 + row];
        O += bf2f(Og[(size_t)(slot0 + k) * 4096 + row * 64 + lane]);
    }
    float tv = O / L;
    float n2 = tv * tv;
#pragma unroll
    for (int o = 1; o < 64; o <<= 1) n2 += __shfl_xor(n2, o);
    float nt   = fmaxf(sqrtf(n2), EPSF);
    float f1   = tanhf(sc * nt) / (sc * nt);
    float ny   = fmaxf(f1 * sqrtf(n2), EPSF);
    float ncl  = fminf(ny, inv_sc - EPSF);
    float coef = atanhf(sc * ncl) / (sc * ny);
    conc[(size_t)i * 1024 + h * 64 + lane] = f2bf(coef * f1 * tv);
}

// ---------------- launch (exact r19 pipeline — best verified: 121.58 us) ----------------
// ws layout (peak < 37.2 MB; proven zone):
//   0-4: Vtg (transposed by QKV GEMM) | 4-8: Qtb (mapped) | 8-12: Ktb (mapped)
//   12-16: concb | 16-16.5: xns/yns/xds/yds | 16.5-18.5: wob | 18.5-22.5: xb
//   22.5-28.5: wqb|wkb|wvb | 18.5-36.5: Og (reuses dead xb/w*) | 36.5-37.1: ml
extern "C" void kernel_launch(void* const* d_in, const int* in_sizes, int n_in,
                              void* d_out, int out_size, void* d_ws, size_t ws_size,
                              hipStream_t stream) {
    const float* x     = (const float*)d_in[0];
    const float* Wq    = (const float*)d_in[1];
    const float* Wk    = (const float*)d_in[2];
    const float* Wv    = (const float*)d_in[3];
    const float* Wo    = (const float*)d_in[4];
    const float* pLogC = (const float*)d_in[5];
    const float* pBeta = (const float*)d_in[6];
    float* out = (float*)d_out;

    char* w = (char*)d_ws;
    unsigned short* Vtg   = (unsigned short*)(w);
    unsigned short* Qtb   = (unsigned short*)(w + (4u  << 20));
    unsigned short* Ktb   = (unsigned short*)(w + (8u  << 20));
    unsigned short* concb = (unsigned short*)(w + (12u << 20));
    float*          xns   = (float*)(w + (16u << 20));
    float*          yns   = (float*)(w + (16u << 20) + (1u << 17));
    float*          xds   = (float*)(w + (16u << 20) + (2u << 17));
    float*          yds   = (float*)(w + (16u << 20) + (3u << 17));
    unsigned short* wob   = (unsigned short*)(w + (16u << 20) + (1u << 19));
    unsigned short* xb    = (unsigned short*)(w + (18u << 20) + (1u << 19));
    unsigned short* wqb   = (unsigned short*)(w + (22u << 20) + (1u << 19));
    unsigned short* wkb   = (unsigned short*)(w + (24u << 20) + (1u << 19));
    unsigned short* wvb   = (unsigned short*)(w + (26u << 20) + (1u << 19));
    unsigned short* Og    = (unsigned short*)(w + (18u << 20) + (1u << 19));
    float*          ml    = (float*)(w + (36u << 20) + (1u << 19));

    k_f2b_all<<<2048, 256, 0, stream>>>(x, Wq, Wk, Wv, Wo, xb, wqb, wkb, wvb, wob);

    // fused QKV projection + exp_map (mapped Q/K + stats) + transposed V
    k_gemm_qkv<<<768, 256, 0, stream>>>(xb, wqb, Qtb, Ktb, Vtg,
                                        xns, xds, yns, yds, pLogC,
                                        2048, 3072, 1024);

    k_attn_part<<<2304, 256, 0, stream>>>(Qtb, Ktb, Vtg, xns, xds, yns, yds,
                                          pLogC, pBeta, Og, ml, concb);

    k_merge<<<7168, 256, 0, stream>>>(Og, ml, pLogC, concb);

    // output GEMM: 64x64 tiles, grid 512 = 2 blocks/CU (r17-verified)
    k_gemm64<<<512, 256, 0, stream>>>(concb, wob, out, 2048, 1024, 1024);
}